// Round 10
// baseline (417.140 us; speedup 1.0000x reference)
//
#include <hip/hip_runtime.h>
#include <hip/hip_bf16.h>

#define D 512
#define L_LAYERS 2
#define BATCH 8
#define TT 2048
#define N3 1536   // 3*D
#define REC 4096  // BATCH*D
#define HALF_IDX (1024 * 1024)   // idx of t=1024 in (t*1024+q) space

typedef __attribute__((ext_vector_type(8))) short short8;
typedef __attribute__((ext_vector_type(4))) float floatx4;

#if __has_builtin(__builtin_amdgcn_exp2f)
#define EXP2F(x) __builtin_amdgcn_exp2f(x)
#else
#define EXP2F(x) exp2f(x)
#endif
#if __has_builtin(__builtin_amdgcn_rcpf)
#define RCPF(x) __builtin_amdgcn_rcpf(x)
#else
#define RCPF(x) (1.0f / (x))
#endif

__device__ __forceinline__ unsigned short f2bf(float f) {
  unsigned u = __builtin_bit_cast(unsigned, f);
  u += 0x7FFFu + ((u >> 16) & 1u);
  return (unsigned short)(u >> 16);
}

// ---- merged prefix: embed (blocks 0..8191, 2 bt each) + W transpose
// (blocks 8192..14335) + per-batch len (block 8192, threads 248..255).
__global__ __launch_bounds__(256) void ew_kernel(const int* __restrict__ ids,
                                                 const float* __restrict__ emb,
                                                 unsigned short* __restrict__ xa,
                                                 const float* __restrict__ Ws,
                                                 unsigned short* __restrict__ Wt,
                                                 const void* __restrict__ maskp,
                                                 int* __restrict__ lenb) {
  int bi = blockIdx.x;
  int tid = threadIdx.x;
  if (bi < 8192) {
    int bt = bi * 2 + (tid >> 7);   // b*T + t
    int b = bt >> 11;
    int t = bt & 2047;
    int id = ids[bt];
    int d = (tid & 127) << 2;
    const float4 v = *(const float4*)(emb + (size_t)id * D + d);
    ushort4 w;
    w.x = f2bf(v.x); w.y = f2bf(v.y); w.z = f2bf(v.z); w.w = f2bf(v.w);
    *(ushort4*)(xa + ((size_t)t * BATCH + b) * D + d) = w;
    return;
  }
  if (bi == 8192 && tid >= 248) {
    int b = tid - 248;
    int w0 = *(const int*)maskp;
    int mode = (w0 == 1) ? 0 : ((w0 == 0x01010101) ? 1 : 2);  // i32 / u8 / f32
    int lo = 0, hi = TT;
    while (lo < hi) {
      int mid = (lo + hi) >> 1;
      int idx = b * TT + mid;
      bool mm = (mode == 0) ? (((const int*)maskp)[idx] != 0)
              : (mode == 1) ? (((const unsigned char*)maskp)[idx] != 0)
                            : (((const float*)maskp)[idx] != 0.f);
      if (mm) lo = mid + 1; else hi = mid;
    }
    lenb[b] = lo;
  }
  int idx = (bi - 8192) * 256 + tid;
  if (idx >= L_LAYERS * D * N3) return;
  int n = idx % N3;
  int k = (idx / N3) % D;
  int l = idx / (N3 * D);
  Wt[((size_t)l * N3 + n) * D + k] = f2bf(Ws[idx]);
}

// ==== GEMM body, BM=64 tile, 3-plane, 2-phase double-buffered.
// bi in [0,512): xcd=bi&7, j=bi>>3 (0..63), bm = bm_base + xcd*16 + (j>>2)
// (64-row tiles), dc0=(j&3)*128.  512 threads / 8 waves; wave w covers all
// 64 m-rows x cols [w*48,(w+1)*48) = the 3 planes of dcols [dc0+w*16,+16):
// col c -> g=c>>4 = 3w+ni -> plane p=ni, dcol = dc0 + w*16 + (c&15).
// acc[4][3], 12 MFMA/iter, 16 iters. LDS 2*(4KB As + 24KB Bs) = 56KB -> 2/CU.
// Outputs: Ua[rec] u32 = u0|u1<<16, Uc[rec] u16 = u2  (rec = m*512+dcol).
__device__ __forceinline__ void gemm_body(int bi, int bm_base,
                                          const unsigned short* __restrict__ A,
                                          const unsigned short* __restrict__ Bt,
                                          unsigned* __restrict__ Ua32,
                                          unsigned short* __restrict__ Uc16,
                                          unsigned short* As,    // 2*2048
                                          unsigned short* Bs) {  // 2*12288
  constexpr int K = D;
  int tid = threadIdx.x;
  int lane = tid & 63;
  int wave = tid >> 6;           // 0..7
  int xcd = bi & 7;
  int j = bi >> 3;               // 0..63
  int bm = bm_base + xcd * 16 + (j >> 2);
  int dc0 = (j & 3) * 128;
  int m0 = bm * 64;
  int q = lane >> 4, r16 = lane & 15;

  // Bs staging (identical pattern to proven R6/R9): 3 slots/thread
  int arow = tid >> 2;           // 0..127
  int aoff = (tid & 3) * 8;
  int nsrc[3];
#pragma unroll
  for (int i = 0; i < 3; ++i) {
    int c = arow + i * 128;      // Bs column 0..383
    int g = c >> 4;
    int p = g % 3;
    int dcol = (g / 3) * 16 + (c & 15);
    nsrc[i] = dc0 + dcol + p * 512;
  }
  // As staging: 64 rows x 32 cols = 256 x 16B slots, tid<256 only
  const unsigned short* asrc = A + (size_t)(m0 + (tid >> 2)) * K + aoff;

  floatx4 acc[4][3] = {};

#define GSTAGE(bufi, k0s)                                                                  \
  {                                                                                        \
    if (tid < 256)                                                                         \
      __builtin_amdgcn_global_load_lds(                                                    \
          (const __attribute__((address_space(1))) unsigned int*)(asrc + (k0s)),           \
          (__attribute__((address_space(3))) unsigned int*)(As + (bufi) * 2048 + tid * 8), 16, 0, 0); \
    _Pragma("unroll")                                                                      \
    for (int i = 0; i < 3; ++i) {                                                          \
      __builtin_amdgcn_global_load_lds(                                                    \
          (const __attribute__((address_space(1))) unsigned int*)(Bt + (size_t)nsrc[i] * K + (k0s) + aoff), \
          (__attribute__((address_space(3))) unsigned int*)(Bs + (bufi) * 12288 + i * 4096 + tid * 8), 16, 0, 0); \
    }                                                                                      \
  }

  GSTAGE(0, 0);
  __syncthreads();
  int cur = 0;
  for (int k0 = 0; k0 < K; k0 += 32) {
    if (k0 + 32 < K) GSTAGE(cur ^ 1, k0 + 32);
    short8 af[4], bfr[3];
#pragma unroll
    for (int i = 0; i < 4; ++i)
      af[i] = *(const short8*)&As[cur * 2048 + (i * 16 + r16) * 32 + q * 8];
#pragma unroll
    for (int i = 0; i < 3; ++i)
      bfr[i] = *(const short8*)&Bs[cur * 12288 + (wave * 48 + i * 16 + r16) * 32 + q * 8];
#pragma unroll
    for (int mi = 0; mi < 4; ++mi)
#pragma unroll
      for (int ni = 0; ni < 3; ++ni)
        acc[mi][ni] = __builtin_amdgcn_mfma_f32_16x16x32_bf16(af[mi], bfr[ni], acc[mi][ni], 0, 0, 0);
    __syncthreads();
    cur ^= 1;
  }
#undef GSTAGE

  // epilogue: C/D layout col=lane&15, row=(lane>>4)*4+reg (verified m89/m91)
  int dcol = dc0 + wave * 16 + r16;
#pragma unroll
  for (int mi = 0; mi < 4; ++mi)
#pragma unroll
    for (int i = 0; i < 4; ++i) {
      int m = m0 + mi * 16 + q * 4 + i;
      size_t rec = (size_t)m * D + dcol;
      unsigned ua = (unsigned)f2bf(acc[mi][0][i]) |
                    ((unsigned)f2bf(acc[mi][1][i]) << 16);
      Ua32[rec] = ua;
      Uc16[rec] = f2bf(acc[mi][2][i]);
    }
}

// ==== chain body (proven R9), t-ranged [t0,t1), + setprio(1) (T5: protect
// the latency-critical wave from co-resident throughput waves).
__device__ __forceinline__ void chain_body(unsigned* __restrict__ Uac,
                                           const float* __restrict__ vsl,
                                           const float* __restrict__ bsl,
                                           const int* __restrict__ lenb,
                                           float* __restrict__ csave,
                                           int ch, int t0, int t1) {
  __builtin_amdgcn_s_setprio(1);
  int b = ch >> 9;
  int d = ch & 511;
  int len = lenb[b];
  const float NL2E = -1.4426950408889634f;
  float vfe = NL2E * vsl[d];
  float cbf = NL2E * bsl[d];
  const unsigned* pa = Uac + ch;
  float* pc = (float*)Uac + ch;
  int nact = (len + 31) >> 5;
  int kbeg = t0 >> 5;
  int kend = t1 >> 5;
  if (nact < kend) kend = nact;

  unsigned uA[32], uB[32];

#define CLOAD(k, u)                                         \
  _Pragma("unroll") for (int j = 0; j < 32; ++j)            \
      u[j] = pa[(size_t)((k) * 32 + j) * REC];

#define CCOMP(k, u)                                         \
  _Pragma("unroll") for (int j = 0; j < 32; ++j) {          \
    unsigned a = u[j];                                      \
    float u0 = __builtin_bit_cast(float, a << 16);          \
    float u1f = __builtin_bit_cast(float, a & 0xFFFF0000u); \
    float k1 = fmaf(u1f, NL2E, cbf);                        \
    float a2 = fmaf(vfe, c, k1);                            \
    float e = EXP2F(a2);                                    \
    float inv = RCPF(e + 1.f);                              \
    c = fmaf(c - u0, inv, u0);                              \
    pc[(size_t)((k) * 32 + j) * REC] = c;                   \
  }

  float c = (t0 == 0) ? 0.f : csave[ch];
  if (kbeg < kend) {
    CLOAD(kbeg, uA);
    int k = kbeg;
    for (;;) {
      if (k + 1 < kend) CLOAD(k + 1, uB);
      CCOMP(k, uA);
      if (++k >= kend) break;
      if (k + 1 < kend) CLOAD(k + 1, uA);
      CCOMP(k, uB);
      if (++k >= kend) break;
    }
  }
#undef CLOAD
#undef CCOMP
  if (t1 < TT) csave[ch] = c;
  __builtin_amdgcn_s_setprio(0);
  // t >= nact*32: c stale; hpost masks h=0 there.
}

// ==== hpost body (proven R6/R9), idx-parameterized. idx = t*1024 + q.
template <bool LAST>
__device__ __forceinline__ void hpost_body(int idx,
                                           const unsigned short* __restrict__ Uc,
                                           const unsigned short* __restrict__ Xin,
                                           const float4* __restrict__ cq,
                                           const float* __restrict__ vsl,
                                           const float* __restrict__ bsl,
                                           const int* __restrict__ lenb,
                                           unsigned short* __restrict__ Hout,
                                           float* __restrict__ Out) {
  int t = idx >> 10;
  int q = idx & 1023;
  int rec0 = q << 2;
  int b = rec0 >> 9;
  int d = rec0 & 511;
  int len = lenb[b];
  ushort4 uv = *(const ushort4*)(Uc + (size_t)idx * 4);
  ushort4 xv = *(const ushort4*)(Xin + (size_t)idx * 4);
  float4 ct = cq[idx];
  float4 cp = (t > 0) ? cq[idx - 1024] : make_float4(0.f, 0.f, 0.f, 0.f);
  float4 vr4 = *(const float4*)(vsl + D + d);
  float4 br4 = *(const float4*)(bsl + D + d);
  const float NL2E = -1.4426950408889634f;
  const float L2E2 = 2.8853900817779268f;
  unsigned uu[4] = {uv.x, uv.y, uv.z, uv.w};
  unsigned xx[4] = {xv.x, xv.y, xv.z, xv.w};
  float cta[4] = {ct.x, ct.y, ct.z, ct.w};
  float cpa[4] = {cp.x, cp.y, cp.z, cp.w};
  float vra[4] = {vr4.x, vr4.y, vr4.z, vr4.w};
  float bra[4] = {br4.x, br4.y, br4.z, br4.w};
  bool act = t < len;
  float h[4];
#pragma unroll
  for (int j = 0; j < 4; ++j) {
    float u2 = __builtin_bit_cast(float, uu[j] << 16);
    float xf = __builtin_bit_cast(float, xx[j] << 16);
    float k2 = fmaf(u2, NL2E, NL2E * bra[j]);
    float a2 = fmaf(NL2E * vra[j], cpa[j], k2);
    float r = RCPF(EXP2F(a2) + 1.f);
    float et = EXP2F(cta[j] * L2E2);
    float th = fmaf(-2.f, RCPF(et + 1.f), 1.f);
    float hv = fmaf(r, th - xf, xf);
    h[j] = act ? hv : 0.f;
  }
  if (LAST) {
    *(float4*)(Out + ((size_t)b * TT + t) * D + d) = make_float4(h[0], h[1], h[2], h[3]);
  } else {
    ushort4 o; o.x = f2bf(h[0]); o.y = f2bf(h[1]); o.z = f2bf(h[2]); o.w = f2bf(h[3]);
    *(ushort4*)(Hout + (size_t)idx * 4) = o;
  }
}

// ==== K1: pure GEMM piece (512 blocks), bm 64-row tiles [bm_base, +128)
__global__ __launch_bounds__(512) void gemm_kernel(const unsigned short* __restrict__ A,
                                                   const unsigned short* __restrict__ Bt,
                                                   unsigned* __restrict__ Ua32,
                                                   unsigned short* __restrict__ Uc16,
                                                   int bm_base) {
  __shared__ __align__(16) unsigned short As[2 * 2048];
  __shared__ __align__(16) unsigned short Bs[2 * 12288];
  gemm_body(blockIdx.x, bm_base, A, Bt, Ua32, Uc16, As, Bs);
}

// ==== K2: chain t<1024 (blocks 0..63) || GEMM t>=1024 (blocks 64..575).
__global__ __launch_bounds__(512) void gc_kernel(const unsigned short* __restrict__ A,
                                                 const unsigned short* __restrict__ Bt,
                                                 unsigned* __restrict__ Ua32,
                                                 unsigned short* __restrict__ Uc16,
                                                 const float* __restrict__ vsl,
                                                 const float* __restrict__ bsl,
                                                 const int* __restrict__ lenb,
                                                 float* __restrict__ csave) {
  __shared__ __align__(16) unsigned short As[2 * 2048];
  __shared__ __align__(16) unsigned short Bs[2 * 12288];
  int bi = blockIdx.x;
  if (bi < 64) {
    if (threadIdx.x >= 64) return;
    chain_body(Ua32, vsl, bsl, lenb, csave, bi * 64 + threadIdx.x, 0, 1024);
  } else {
    gemm_body(bi - 64, 128, A, Bt, Ua32, Uc16, As, Bs);
  }
}

// ==== K3: chain t>=1024 (blocks 0..63) || hpost t<1024 (blocks 64..4159).
template <bool LAST>
__global__ __launch_bounds__(256) void ch_kernel(unsigned* __restrict__ Uac,
                                                 const unsigned short* __restrict__ Uc,
                                                 const unsigned short* __restrict__ Xin,
                                                 const float* __restrict__ vsl,
                                                 const float* __restrict__ bsl,
                                                 const int* __restrict__ lenb,
                                                 float* __restrict__ csave,
                                                 unsigned short* __restrict__ Hout,
                                                 float* __restrict__ Out) {
  int bi = blockIdx.x;
  if (bi < 64) {
    if (threadIdx.x >= 64) return;
    chain_body(Uac, vsl, bsl, lenb, csave, bi * 64 + threadIdx.x, 1024, 2048);
  } else {
    hpost_body<LAST>((bi - 64) * 256 + threadIdx.x, Uc, Xin, (const float4*)Uac,
                     vsl, bsl, lenb, Hout, Out);
  }
}

// ==== K4 (layer seam): hpost_l0 t>=1024 (blocks 0..2047, writes xb t>=1024)
// || gemm_l1 t<1024 (blocks 2048..2559, reads xb t<1024). Disjoint xb rows.
__global__ __launch_bounds__(512) void hg_kernel(const unsigned short* __restrict__ Uc,
                                                 const unsigned short* __restrict__ Xin,
                                                 const unsigned* __restrict__ UacPrev,
                                                 const float* __restrict__ vsl0,
                                                 const float* __restrict__ bsl0,
                                                 const int* __restrict__ lenb,
                                                 unsigned short* __restrict__ Hout,
                                                 const unsigned short* __restrict__ A1,
                                                 const unsigned short* __restrict__ Bt1,
                                                 unsigned* __restrict__ Ua32,
                                                 unsigned short* __restrict__ Uc16) {
  __shared__ __align__(16) unsigned short As[2 * 2048];
  __shared__ __align__(16) unsigned short Bs[2 * 12288];
  int bi = blockIdx.x;
  if (bi < 2048) {
    hpost_body<false>(HALF_IDX + bi * 512 + threadIdx.x, Uc, Xin,
                      (const float4*)UacPrev, vsl0, bsl0, lenb, Hout, nullptr);
  } else {
    gemm_body(bi - 2048, 0, A1, Bt1, Ua32, Uc16, As, Bs);
  }
}

// ==== K5: final hpost, t >= 1024 (512 threads)
__global__ __launch_bounds__(512) void hpost_kernel(const unsigned short* __restrict__ Uc,
                                                    const unsigned short* __restrict__ Xin,
                                                    const float4* __restrict__ cq,
                                                    const float* __restrict__ vsl,
                                                    const float* __restrict__ bsl,
                                                    const int* __restrict__ lenb,
                                                    float* __restrict__ Out) {
  hpost_body<true>(HALF_IDX + blockIdx.x * 512 + threadIdx.x, Uc, Xin, cq,
                   vsl, bsl, lenb, nullptr, Out);
}

extern "C" void kernel_launch(void* const* d_in, const int* in_sizes, int n_in,
                              void* d_out, int out_size, void* d_ws, size_t ws_size,
                              hipStream_t stream) {
  const int* ids = (const int*)d_in[0];
  const void* mask = d_in[1];
  const float* emb = (const float*)d_in[2];
  const float* Ws = (const float*)d_in[3];
  const float* vs = (const float*)d_in[4];
  const float* bs = (const float*)d_in[5];
  float* out = (float*)d_out;

  char* ws = (char*)d_ws;
  unsigned short* Ua = (unsigned short*)ws;                   // 33.5 MB dword/rec (u0|u1; later c as f32)
  unsigned short* Uc = Ua + (size_t)TT * REC * 2;             // 16.8 MB ushort/rec (u2)
  unsigned short* xa = Uc + (size_t)TT * REC;                 // 16.8 MB
  unsigned short* xb = xa + (size_t)TT * REC;                 // 16.8 MB
  unsigned short* Wt = xb + (size_t)TT * REC;                 // 3.1 MB
  int* lenb = (int*)(Wt + (size_t)L_LAYERS * D * N3);
  float* csave = (float*)(lenb + 16);                         // 4096 f32 = 16 KB

  const unsigned short* Wt1 = Wt + (size_t)N3 * D;

  // prefix (embed || wconv || len)
  ew_kernel<<<14336, 256, 0, stream>>>(ids, emb, xa, Ws, Wt, mask, lenb);

  // layer 0 pipeline
  gemm_kernel<<<512, 512, 0, stream>>>(xa, Wt, (unsigned*)Ua, Uc, 0);
  gc_kernel<<<576, 512, 0, stream>>>(xa, Wt, (unsigned*)Ua, Uc, vs, bs, lenb, csave);
  ch_kernel<false><<<4160, 256, 0, stream>>>((unsigned*)Ua, Uc, xa, vs, bs, lenb,
                                             csave, xb, nullptr);
  // layer seam: hpost_l0 h2 || gemm_l1 h1
  hg_kernel<<<2560, 512, 0, stream>>>(Uc, xa, (const unsigned*)Ua, vs, bs, lenb, xb,
                                      xb, Wt1, (unsigned*)Ua, Uc);
  // layer 1 pipeline
  gc_kernel<<<576, 512, 0, stream>>>(xb, Wt1, (unsigned*)Ua, Uc,
                                     vs + 2 * D, bs + 2 * D, lenb, csave);
  ch_kernel<true><<<4160, 256, 0, stream>>>((unsigned*)Ua, Uc, xb, vs + 2 * D, bs + 2 * D,
                                            lenb, csave, nullptr, out);
  hpost_kernel<<<2048, 512, 0, stream>>>(Uc, xb, (const float4*)Ua,
                                         vs + 2 * D, bs + 2 * D, lenb, out);
}